// Round 3
// baseline (526.785 us; speedup 1.0000x reference)
//
#include <hip/hip_runtime.h>
#include <hip/hip_bf16.h>
#include <float.h>

// Problem constants
#define BQ 512     // batch
#define LQ 12      // L
#define DQ 768     // D
#define TQ 20      // tasks
#define NKQ 100    // keys per task
#define NPQ 10     // prompts per task
#define NKEY (TQ*NKQ)   // 2000 keys per l

// argmin kernel tiling
#define BT 128     // b per block
#define KT 128     // keys per block (= chunk)
#define DT 16      // d chunk (25 KB LDS -> 6 blocks/CU)
#define NCH 16     // ceil(2000/128)
#define GS 12      // LDS group stride: 8 data + 4 pad words (16B-aligned groups)
#define RS (16*GS + 4)   // d-row stride in words = 196 (== 4 mod 32)

// idx into transposed group-padded LDS tile: depth d, row r (b or k)
__device__ __forceinline__ int lidx(int d, int r) {
    return d * RS + (r >> 3) * GS + (r & 7);
}

// ---------------- K1: k2[l*2000+g] = sum_d keys^2 ----------------
__global__ __launch_bounds__(256)
void k2_kernel(const float* __restrict__ keys, float* __restrict__ k2) {
    int wave = threadIdx.x >> 6;
    int lane = threadIdx.x & 63;
    int row = blockIdx.x * 4 + wave;          // 0 .. 23999
    const float* kp = keys + (size_t)row * DQ;
    float s = 0.f;
#pragma unroll
    for (int c = 0; c < 3; ++c) {
        float4 v = *reinterpret_cast<const float4*>(kp + c * 256 + lane * 4);
        s = fmaf(v.x, v.x, s); s = fmaf(v.y, v.y, s);
        s = fmaf(v.z, v.z, s); s = fmaf(v.w, v.w, s);
    }
#pragma unroll
    for (int m = 32; m; m >>= 1) s += __shfl_xor(s, m, 64);
    if (lane == 0) k2[row] = s;
}

// ---------------- K2: per-(l, b-tile, key-chunk) partial argmin ----------------
// 128b x 128k block tile, 128 threads, 8x16 per-thread tile.
// FMA : LDS-read ratio = 128 : 6xb128  ->  VALU-bound (~85% ceiling).
__global__ __launch_bounds__(128)
void argmin_kernel(const float* __restrict__ xq, const float* __restrict__ keys,
                   const float* __restrict__ k2,
                   float* __restrict__ pval, int* __restrict__ pidx) {
    const int bt    = blockIdx.x;   // 0..3
    const int chunk = blockIdx.y;   // 0..15
    const int l     = blockIdx.z;   // 0..11
    const int tid = threadIdx.x;
    const int tx = tid & 7;         // key dim: 8 lane-groups x 16 keys
    const int ty = tid >> 3;        // b dim: 16 groups x 8 b
    const int b0 = bt * BT;
    const int g0 = chunk * KT;

    __shared__ float Xs[DT * RS];   // [d][b-groups], 12544 B
    __shared__ float Ks[DT * RS];   // [d][k-groups], 12544 B

    float acc[8][16];
#pragma unroll
    for (int i = 0; i < 8; ++i)
#pragma unroll
        for (int j = 0; j < 16; ++j) acc[i][j] = 0.f;

    const int dq = tid & 3;     // float4 slot along d (4*4 = 16)
    const int r0 = tid >> 2;    // 0..31, row base (4 passes of 32)

    for (int dc = 0; dc < DQ / DT; ++dc) {   // 48 d-chunks
        const int d0 = dc * DT;
        // stage X tile: 128 b x 16 d, transposed into Xs[d][b]
#pragma unroll
        for (int p = 0; p < 4; ++p) {
            int r = p * 32 + r0;
            float4 v = *reinterpret_cast<const float4*>(
                &xq[((size_t)(b0 + r) * LQ + l) * DQ + d0 + dq * 4]);
            Xs[lidx(dq * 4 + 0, r)] = v.x;
            Xs[lidx(dq * 4 + 1, r)] = v.y;
            Xs[lidx(dq * 4 + 2, r)] = v.z;
            Xs[lidx(dq * 4 + 3, r)] = v.w;
        }
        // stage K tile: 128 k x 16 d (clamped addr; epilogue guards validity)
#pragma unroll
        for (int p = 0; p < 4; ++p) {
            int r = p * 32 + r0;
            int g = g0 + r; if (g >= NKEY) g = NKEY - 1;
            float4 v = *reinterpret_cast<const float4*>(
                &keys[((size_t)l * NKEY + g) * DQ + d0 + dq * 4]);
            Ks[lidx(dq * 4 + 0, r)] = v.x;
            Ks[lidx(dq * 4 + 1, r)] = v.y;
            Ks[lidx(dq * 4 + 2, r)] = v.z;
            Ks[lidx(dq * 4 + 3, r)] = v.w;
        }
        __syncthreads();
#pragma unroll 2
        for (int d = 0; d < DT; ++d) {
            const float* Xrow = &Xs[d * RS];
            const float* Krow = &Ks[d * RS];
            const float4 xa = *reinterpret_cast<const float4*>(&Xrow[ty * GS]);
            const float4 xb = *reinterpret_cast<const float4*>(&Xrow[ty * GS + 4]);
            const float4 ka = *reinterpret_cast<const float4*>(&Krow[tx * 24]);
            const float4 kb = *reinterpret_cast<const float4*>(&Krow[tx * 24 + 4]);
            const float4 kc = *reinterpret_cast<const float4*>(&Krow[tx * 24 + 12]);
            const float4 kd = *reinterpret_cast<const float4*>(&Krow[tx * 24 + 16]);
            float xr[8]  = {xa.x, xa.y, xa.z, xa.w, xb.x, xb.y, xb.z, xb.w};
            float kr[16] = {ka.x, ka.y, ka.z, ka.w, kb.x, kb.y, kb.z, kb.w,
                            kc.x, kc.y, kc.z, kc.w, kd.x, kd.y, kd.z, kd.w};
#pragma unroll
            for (int i = 0; i < 8; ++i)
#pragma unroll
                for (int j = 0; j < 16; ++j)
                    acc[i][j] = fmaf(xr[i], kr[j], acc[i][j]);
        }
        __syncthreads();
    }

    // epilogue: score = k2 - 2*dot; per-thread min over 16 keys (ascending g)
    float bv[8]; int bi[8];
#pragma unroll
    for (int i = 0; i < 8; ++i) { bv[i] = FLT_MAX; bi[i] = 0x7fffffff; }
#pragma unroll
    for (int j = 0; j < 16; ++j) {
        int g = g0 + tx * 16 + j;
        if (g < NKEY) {
            float kk = k2[l * NKEY + g];
#pragma unroll
            for (int i = 0; i < 8; ++i) {
                float s = fmaf(-2.f, acc[i][j], kk);
                if (s < bv[i]) { bv[i] = s; bi[i] = g; }  // strict < keeps earliest
            }
        }
    }
    // reduce across the 8 key-lanes (tx); tie -> smaller idx
#pragma unroll
    for (int m = 1; m < 8; m <<= 1) {
#pragma unroll
        for (int i = 0; i < 8; ++i) {
            float ov = __shfl_xor(bv[i], m, 64);
            int   oi = __shfl_xor(bi[i], m, 64);
            if (ov < bv[i] || (ov == bv[i] && oi < bi[i])) { bv[i] = ov; bi[i] = oi; }
        }
    }
    if (tx == 0) {
#pragma unroll
        for (int i = 0; i < 8; ++i) {
            int b = b0 + ty * 8 + i;
            size_t o = ((size_t)l * BQ + b) * NCH + chunk;
            pval[o] = bv[i];
            pidx[o] = bi[i];
        }
    }
}

// ---------------- K3: combine partials + gather prompts ----------------
__global__ __launch_bounds__(256)
void gather_kernel(const float* __restrict__ prompts,
                   const float* __restrict__ pval, const int* __restrict__ pidx,
                   float* __restrict__ out) {
    const int b = blockIdx.x;   // 0..511
    const int l = blockIdx.y;   // 0..11
    size_t base = ((size_t)l * BQ + b) * NCH;
    float bv = FLT_MAX; int bi = 0x7fffffff;
#pragma unroll
    for (int c = 0; c < NCH; ++c) {
        float v = pval[base + c]; int idx = pidx[base + c];
        if (v < bv || (v == bv && idx < bi)) { bv = v; bi = idx; }
    }
    int task = bi / NKQ;
    const float4* src = reinterpret_cast<const float4*>(
        prompts + ((size_t)l * TQ + task) * (NPQ * DQ));
    float4* dst = reinterpret_cast<float4*>(
        out + ((size_t)l * BQ + b) * (size_t)(NPQ * DQ));
    const int n4 = NPQ * DQ / 4;  // 1920
    for (int i = threadIdx.x; i < n4; i += blockDim.x) dst[i] = src[i];
    if (b == 0 && l == 0 && threadIdx.x == 0)
        out[(size_t)LQ * BQ * NPQ * DQ] = 0.0f;   // trailing scalar output (0.0)
}

extern "C" void kernel_launch(void* const* d_in, const int* in_sizes, int n_in,
                              void* d_out, int out_size, void* d_ws, size_t ws_size,
                              hipStream_t stream) {
    const float* xq      = (const float*)d_in[0];  // (B,L,D)
    const float* keys    = (const float*)d_in[1];  // (L,T,NK,D)
    const float* prompts = (const float*)d_in[2];  // (L,T,NP,D)
    float* out = (float*)d_out;

    // workspace layout (floats): [0,24000) k2 | [24064, +98304) pval | then pidx
    float* k2   = (float*)d_ws;
    float* pval = (float*)d_ws + 24064;
    int*   pidx = (int*)((float*)d_ws + 24064 + 98304);

    hipLaunchKernelGGL(k2_kernel, dim3((LQ * NKEY) / 4), dim3(256), 0, stream, keys, k2);
    hipLaunchKernelGGL(argmin_kernel, dim3(4, NCH, LQ), dim3(128), 0, stream,
                       xq, keys, k2, pval, pidx);
    hipLaunchKernelGGL(gather_kernel, dim3(BQ, LQ), dim3(256), 0, stream,
                       prompts, pval, pidx, out);
}